// Round 1
// baseline (44.836 us; speedup 1.0000x reference)
//
#include <hip/hip_runtime.h>

#define G 16
#define T 4096
#define DD 64
#define NB 64   // 64-row blocks per head

typedef __attribute__((ext_vector_type(8))) short bf16x8;
typedef __attribute__((ext_vector_type(4))) float f32x4;
typedef unsigned short U16;

__device__ __forceinline__ float bf2f(U16 u) {
  union { unsigned int u; float f; } x; x.u = ((unsigned int)u) << 16; return x.f;
}
__device__ __forceinline__ U16 f2bf(float f) {
  union { float f; unsigned int u; } x; x.f = f;
  unsigned int r = x.u + 0x7FFFu + ((x.u >> 16) & 1u);
  return (U16)(r >> 16);
}

#define MFMA(a, b, c) __builtin_amdgcn_mfma_f32_16x16x32_bf16((a), (b), (c), 0, 0, 0)

// ln(10000)/32
#define ROPE_C 0.28782313662425575f

// ---------------- Phase 0: RoPE(Q) -> bf16 Qr ----------------
__global__ __launch_bounds__(256) void k_rope_q(const float* __restrict__ Q, U16* __restrict__ Qr) {
  int idx = blockIdx.x * 256 + threadIdx.x;     // G*T*4 = 262144 threads
  int qq = idx & 3;
  int t  = (idx >> 2) & (T - 1);
  int g  = idx >> 14;
  size_t base = ((size_t)g * T + t) * DD;
  int d0 = qq * 8;
  const float* rp = Q + base;
  bf16x8 v1, v2;
#pragma unroll
  for (int i = 0; i < 8; ++i) {
    int d = d0 + i;
    float x1 = rp[d], x2 = rp[d + 32];
    float invf = expf(-(float)d * ROPE_C);
    float ang = (float)t * invf;
    float s = sinf(ang), c = cosf(ang);
    v1[i] = (short)f2bf(x1 * c - x2 * s);
    v2[i] = (short)f2bf(x1 * s + x2 * c);
  }
  *(bf16x8*)(Qr + base + d0)      = v1;
  *(bf16x8*)(Qr + base + d0 + 32) = v2;
}

// ---------------- Phase 1: RoPE(K) -> Kr; M'_b[e][d] = sum_k V[k][e]*Kr[k][d] ----------------
__global__ __launch_bounds__(256) void k_phase1(const float* __restrict__ K, const float* __restrict__ V,
                                                U16* __restrict__ Kr, U16* __restrict__ Xu) {
  __shared__ __align__(16) U16 KrT[64][72];   // [d][k]
  __shared__ __align__(16) U16 VT[64][72];    // [e][k]
  int wid = blockIdx.x;            // g*NB + b
  int g = wid >> 6, b = wid & 63;
  int k0 = b * 64;
  int tid = threadIdx.x;

  // rope K rows -> global Kr (bf16) + LDS KrT (transposed)
  {
    int r = tid >> 2, qq = tid & 3, d0 = qq * 8;
    int t = k0 + r;
    size_t base = ((size_t)g * T + t) * DD;
    const float* rp = K + base;
    bf16x8 v1, v2;
#pragma unroll
    for (int i = 0; i < 8; ++i) {
      int d = d0 + i;
      float x1 = rp[d], x2 = rp[d + 32];
      float invf = expf(-(float)d * ROPE_C);
      float ang = (float)t * invf;
      float s = sinf(ang), c = cosf(ang);
      float o1 = x1 * c - x2 * s;
      float o2 = x1 * s + x2 * c;
      U16 b1 = f2bf(o1), b2 = f2bf(o2);
      v1[i] = (short)b1; v2[i] = (short)b2;
      KrT[d][r]      = b1;
      KrT[d + 32][r] = b2;
    }
    *(bf16x8*)(Kr + base + d0)      = v1;
    *(bf16x8*)(Kr + base + d0 + 32) = v2;
  }
  // stage V transposed -> VT[e][k]
  {
    int c = tid & 63, r0 = (tid >> 6) * 16;
#pragma unroll
    for (int h = 0; h < 2; ++h) {
      bf16x8 tv;
#pragma unroll
      for (int i = 0; i < 8; ++i)
        tv[i] = (short)f2bf(V[((size_t)g * T + k0 + r0 + h * 8 + i) * DD + c]);
      *(bf16x8*)&VT[c][r0 + h * 8] = tv;
    }
  }
  __syncthreads();

  int lane = tid & 63, wv = tid >> 6;
  int lr = lane & 15, lg = lane >> 4;
  bf16x8 A0 = *(const bf16x8*)&VT[16 * wv + lr][8 * lg];
  bf16x8 A1 = *(const bf16x8*)&VT[16 * wv + lr][8 * lg + 32];
#pragma unroll
  for (int dt = 0; dt < 4; ++dt) {
    bf16x8 B0 = *(const bf16x8*)&KrT[16 * dt + lr][8 * lg];
    bf16x8 B1 = *(const bf16x8*)&KrT[16 * dt + lr][8 * lg + 32];
    f32x4 acc = {0.f, 0.f, 0.f, 0.f};
    acc = MFMA(A0, B0, acc);
    acc = MFMA(A1, B1, acc);
#pragma unroll
    for (int rr = 0; rr < 4; ++rr) {
      int e = 16 * wv + 4 * lg + rr, d = 16 * dt + lr;
      Xu[((size_t)wid << 12) + e * 64 + d] = f2bf(acc[rr]);
    }
  }
}

// ---------------- Phase 2: in-place exclusive prefix over the 64 block matrices per head ----------------
__global__ __launch_bounds__(256) void k_phase2(U16* __restrict__ Xu) {
  int g = blockIdx.x >> 4, slice = blockIdx.x & 15;
  int e = slice * 256 + threadIdx.x;
  size_t base = ((size_t)g << 18) + e;     // g*64*4096 + e
  float run = 0.f;
#pragma unroll
  for (int grp = 0; grp < 8; ++grp) {
    U16 v[8];
#pragma unroll
    for (int i = 0; i < 8; ++i)
      v[i] = Xu[base + ((size_t)(grp * 8 + i) << 12)];
#pragma unroll
    for (int i = 0; i < 8; ++i) {
      float f = bf2f(v[i]);
      Xu[base + ((size_t)(grp * 8 + i) << 12)] = f2bf(run);
      run += f;
    }
  }
}

// ---------------- Phase 3: O_b = Qr_b * Sp_b + tril_strict(Qr_b Kr_b^T) V_b ----------------
__global__ __launch_bounds__(256) void k_phase3(const U16* __restrict__ Qr, const U16* __restrict__ Kr,
                                                const float* __restrict__ V, const U16* __restrict__ Xu,
                                                float* __restrict__ Out) {
  __shared__ __align__(16) U16 SP[64][72];     // Sp^T stored [e][d]
  __shared__ __align__(16) U16 VT[64][72];     // [e][k]
  __shared__ __align__(16) U16 SW[4][16][72];  // per-wave masked S round-trip
  int wid = blockIdx.x;
  int g = wid >> 6, b = wid & 63;
  int k0 = b * 64;
  int tid = threadIdx.x;

  // stage Sp^T (linear copy, layout already [e][d])
  {
    int r = tid >> 2, c0 = (tid & 3) * 16;
    const U16* src = Xu + ((size_t)wid << 12) + r * 64 + c0;
    *(bf16x8*)&SP[r][c0]     = *(const bf16x8*)src;
    *(bf16x8*)&SP[r][c0 + 8] = *(const bf16x8*)(src + 8);
  }
  // stage V transposed
  {
    int c = tid & 63, r0 = (tid >> 6) * 16;
#pragma unroll
    for (int h = 0; h < 2; ++h) {
      bf16x8 tv;
#pragma unroll
      for (int i = 0; i < 8; ++i)
        tv[i] = (short)f2bf(V[((size_t)g * T + k0 + r0 + h * 8 + i) * DD + c]);
      *(bf16x8*)&VT[c][r0 + h * 8] = tv;
    }
  }
  __syncthreads();

  int lane = tid & 63, wv = tid >> 6;
  int lr = lane & 15, lg = lane >> 4;
  int q0 = k0 + 16 * wv;

  const U16* qrow = Qr + ((size_t)g * T + q0 + lr) * DD;
  bf16x8 Aq0 = *(const bf16x8*)(qrow + 8 * lg);
  bf16x8 Aq1 = *(const bf16x8*)(qrow + 8 * lg + 32);

  f32x4 O[4];
#pragma unroll
  for (int et = 0; et < 4; ++et) O[et] = (f32x4){0.f, 0.f, 0.f, 0.f};

  // term 1: Qr * Sp
#pragma unroll
  for (int et = 0; et < 4; ++et) {
    bf16x8 B0 = *(const bf16x8*)&SP[16 * et + lr][8 * lg];
    bf16x8 B1 = *(const bf16x8*)&SP[16 * et + lr][8 * lg + 32];
    O[et] = MFMA(Aq0, B0, O[et]);
    O[et] = MFMA(Aq1, B1, O[et]);
  }

  // term 2: diagonal block, strict lower mask; k-tiles kt<=wv only
  for (int kt = 0; kt <= wv; ++kt) {
    const U16* krow = Kr + ((size_t)g * T + k0 + 16 * kt + lr) * DD;
    bf16x8 Bk0 = *(const bf16x8*)(krow + 8 * lg);
    bf16x8 Bk1 = *(const bf16x8*)(krow + 8 * lg + 32);
    f32x4 s = {0.f, 0.f, 0.f, 0.f};
    s = MFMA(Aq0, Bk0, s);
    s = MFMA(Aq1, Bk1, s);
#pragma unroll
    for (int rr = 0; rr < 4; ++rr) {
      int qi = 16 * wv + 4 * lg + rr, ki = 16 * kt + lr;
      float val = (qi > ki) ? s[rr] : 0.f;
      SW[wv][4 * lg + rr][16 * kt + lr] = f2bf(val);
    }
  }
  for (int kt = wv + 1; kt < 4; ++kt) {
#pragma unroll
    for (int rr = 0; rr < 4; ++rr)
      SW[wv][4 * lg + rr][16 * kt + lr] = 0;
  }

  // A-fragments of masked S (same-wave LDS round trip; DS ops are in-order per wave)
  bf16x8 As0 = *(const bf16x8*)&SW[wv][lr][8 * lg];
  bf16x8 As1 = *(const bf16x8*)&SW[wv][lr][8 * lg + 32];

  // PV
#pragma unroll
  for (int et = 0; et < 4; ++et) {
    bf16x8 Bv0 = *(const bf16x8*)&VT[16 * et + lr][8 * lg];
    bf16x8 Bv1 = *(const bf16x8*)&VT[16 * et + lr][8 * lg + 32];
    O[et] = MFMA(As0, Bv0, O[et]);
    O[et] = MFMA(As1, Bv1, O[et]);
  }

  // store f32 output
#pragma unroll
  for (int et = 0; et < 4; ++et)
#pragma unroll
    for (int rr = 0; rr < 4; ++rr)
      Out[((size_t)g * T + q0 + 4 * lg + rr) * DD + 16 * et + lr] = O[et][rr];
}

extern "C" void kernel_launch(void* const* d_in, const int* in_sizes, int n_in,
                              void* d_out, int out_size, void* d_ws, size_t ws_size,
                              hipStream_t stream) {
  const float* Q = (const float*)d_in[0];
  const float* K = (const float*)d_in[1];
  const float* V = (const float*)d_in[2];
  float* Out = (float*)d_out;
  U16* W  = (U16*)d_ws;
  U16* Kr = W;                 // G*T*DD bf16 = 8.39 MB
  U16* Qr = W + 4194304;       // 8.39 MB
  U16* Xu = W + 8388608;       // G*NB*64*64 bf16 = 8.39 MB   (total 24 MiB of ws)
  k_rope_q<<<1024, 256, 0, stream>>>(Q, Qr);
  k_phase1<<<G * NB, 256, 0, stream>>>(K, V, Kr, Xu);
  k_phase2<<<256, 256, 0, stream>>>(Xu);
  k_phase3<<<G * NB, 256, 0, stream>>>(Qr, Kr, V, Xu, Out);
}

// Round 2
// 35.740 us; speedup vs baseline: 1.2545x; 1.2545x over previous
//
#include <hip/hip_runtime.h>

#define G 16
#define T 4096
#define DD 64
#define NB 64   // 64-row blocks per head

typedef __attribute__((ext_vector_type(8))) short bf16x8;
typedef __attribute__((ext_vector_type(4))) float f32x4;
typedef unsigned short U16;

__device__ __forceinline__ float bf2f(U16 u) {
  union { unsigned int u; float f; } x; x.u = ((unsigned int)u) << 16; return x.f;
}
__device__ __forceinline__ U16 f2bf(float f) {
  union { float f; unsigned int u; } x; x.f = f;
  unsigned int r = x.u + 0x7FFFu + ((x.u >> 16) & 1u);
  return (U16)(r >> 16);
}

#define MFMA(a, b, c) __builtin_amdgcn_mfma_f32_16x16x32_bf16((a), (b), (c), 0, 0, 0)

// ln(10000)/32
#define ROPE_C 0.28782313662425575f

// ---------------- Phase T: angle table tab[t][j] = (cos, sin), t<4096, j<32 ----------------
__global__ __launch_bounds__(256) void k_tab(float2* __restrict__ tab) {
  int idx = blockIdx.x * 256 + threadIdx.x;   // 131072
  int t = idx >> 5, j = idx & 31;
  float invf = expf(-(float)j * ROPE_C);
  float ang = (float)t * invf;
  tab[idx] = make_float2(cosf(ang), sinf(ang));
}

// ---------------- Phase 1: RoPE(K) -> Kr; M'_b[e][d] = sum_k V[k][e]*Kr[k][d] ----------------
__global__ __launch_bounds__(256) void k_phase1(const float* __restrict__ K, const float* __restrict__ V,
                                                const float2* __restrict__ tab,
                                                U16* __restrict__ Kr, U16* __restrict__ Xu) {
  __shared__ __align__(16) U16 KrT[64][72];   // [d][k]
  __shared__ __align__(16) U16 VT[64][72];    // [e][k]
  int wid = blockIdx.x;            // g*NB + b
  int g = wid >> 6, b = wid & 63;
  int k0 = b * 64;
  int tid = threadIdx.x;

  // rope K rows (table-driven) -> global Kr (bf16) + LDS KrT (transposed)
  {
    int r = tid >> 2, qq = tid & 3, d0 = qq * 8;
    int t = k0 + r;
    size_t base = ((size_t)g * T + t) * DD;
    const float* rp = K + base;
    const float2* tp = tab + t * 32 + d0;
    float x1[8], x2[8];
    *(float4*)&x1[0] = *(const float4*)(rp + d0);
    *(float4*)&x1[4] = *(const float4*)(rp + d0 + 4);
    *(float4*)&x2[0] = *(const float4*)(rp + d0 + 32);
    *(float4*)&x2[4] = *(const float4*)(rp + d0 + 36);
    bf16x8 v1, v2;
#pragma unroll
    for (int i = 0; i < 8; ++i) {
      float2 cs = tp[i];
      float o1 = x1[i] * cs.x - x2[i] * cs.y;
      float o2 = x1[i] * cs.y + x2[i] * cs.x;
      U16 b1 = f2bf(o1), b2 = f2bf(o2);
      v1[i] = (short)b1; v2[i] = (short)b2;
      KrT[d0 + i][r]      = b1;
      KrT[d0 + i + 32][r] = b2;
    }
    *(bf16x8*)(Kr + base + d0)      = v1;
    *(bf16x8*)(Kr + base + d0 + 32) = v2;
  }
  // stage V transposed -> VT[e][k]
  {
    int c = tid & 63, r0 = (tid >> 6) * 16;
#pragma unroll
    for (int h = 0; h < 2; ++h) {
      bf16x8 tv;
#pragma unroll
      for (int i = 0; i < 8; ++i)
        tv[i] = (short)f2bf(V[((size_t)g * T + k0 + r0 + h * 8 + i) * DD + c]);
      *(bf16x8*)&VT[c][r0 + h * 8] = tv;
    }
  }
  __syncthreads();

  int lane = tid & 63, wv = tid >> 6;
  int lr = lane & 15, lg = lane >> 4;
  bf16x8 A0 = *(const bf16x8*)&VT[16 * wv + lr][8 * lg];
  bf16x8 A1 = *(const bf16x8*)&VT[16 * wv + lr][8 * lg + 32];
#pragma unroll
  for (int dt = 0; dt < 4; ++dt) {
    bf16x8 B0 = *(const bf16x8*)&KrT[16 * dt + lr][8 * lg];
    bf16x8 B1 = *(const bf16x8*)&KrT[16 * dt + lr][8 * lg + 32];
    f32x4 acc = {0.f, 0.f, 0.f, 0.f};
    acc = MFMA(A0, B0, acc);
    acc = MFMA(A1, B1, acc);
#pragma unroll
    for (int rr = 0; rr < 4; ++rr) {
      int e = 16 * wv + 4 * lg + rr, d = 16 * dt + lr;
      Xu[((size_t)wid << 12) + e * 64 + d] = f2bf(acc[rr]);
    }
  }
}

// ---------------- Phase 2: in-place exclusive prefix over the 64 block matrices per head ----------------
__global__ __launch_bounds__(256) void k_phase2(U16* __restrict__ Xu) {
  int g = blockIdx.x >> 4, slice = blockIdx.x & 15;
  int e = slice * 256 + threadIdx.x;
  size_t base = ((size_t)g << 18) + e;     // g*64*4096 + e
  float run = 0.f;
#pragma unroll
  for (int grp = 0; grp < 8; ++grp) {
    U16 v[8];
#pragma unroll
    for (int i = 0; i < 8; ++i)
      v[i] = Xu[base + ((size_t)(grp * 8 + i) << 12)];
#pragma unroll
    for (int i = 0; i < 8; ++i) {
      float f = bf2f(v[i]);
      Xu[base + ((size_t)(grp * 8 + i) << 12)] = f2bf(run);
      run += f;
    }
  }
}

// ---------------- Phase 3: O_b = rope(Q)_b * Sp_b + tril_strict(rope(Q)_b Kr_b^T) V_b ----------------
__global__ __launch_bounds__(256) void k_phase3(const float* __restrict__ Q, const U16* __restrict__ Kr,
                                                const float* __restrict__ V, const U16* __restrict__ Xu,
                                                const float2* __restrict__ tab,
                                                float* __restrict__ Out) {
  __shared__ __align__(16) U16 SP[64][72];     // Sp^T stored [e][d]
  __shared__ __align__(16) U16 VT[64][72];     // [e][k]
  __shared__ __align__(16) U16 SW[4][16][72];  // per-wave masked S round-trip
  int wid = blockIdx.x;
  int g = wid >> 6, b = wid & 63;
  int k0 = b * 64;
  int tid = threadIdx.x;

  // stage Sp^T (linear copy, layout already [e][d])
  {
    int r = tid >> 2, c0 = (tid & 3) * 16;
    const U16* src = Xu + ((size_t)wid << 12) + r * 64 + c0;
    *(bf16x8*)&SP[r][c0]     = *(const bf16x8*)src;
    *(bf16x8*)&SP[r][c0 + 8] = *(const bf16x8*)(src + 8);
  }
  // stage V transposed
  {
    int c = tid & 63, r0 = (tid >> 6) * 16;
#pragma unroll
    for (int h = 0; h < 2; ++h) {
      bf16x8 tv;
#pragma unroll
      for (int i = 0; i < 8; ++i)
        tv[i] = (short)f2bf(V[((size_t)g * T + k0 + r0 + h * 8 + i) * DD + c]);
      *(bf16x8*)&VT[c][r0 + h * 8] = tv;
    }
  }

  int lane = tid & 63, wv = tid >> 6;
  int lr = lane & 15, lg = lane >> 4;
  int q0 = k0 + 16 * wv;

  // fused RoPE(Q): load f32 Q row chunk + table, build bf16 A-fragments in-register
  bf16x8 Aq0, Aq1;
  {
    int t = q0 + lr;
    const float* qrow = Q + ((size_t)g * T + t) * DD;
    const float2* tp = tab + t * 32 + 8 * lg;
    float x1[8], x2[8];
    *(float4*)&x1[0] = *(const float4*)(qrow + 8 * lg);
    *(float4*)&x1[4] = *(const float4*)(qrow + 8 * lg + 4);
    *(float4*)&x2[0] = *(const float4*)(qrow + 8 * lg + 32);
    *(float4*)&x2[4] = *(const float4*)(qrow + 8 * lg + 36);
#pragma unroll
    for (int i = 0; i < 8; ++i) {
      float2 cs = tp[i];
      Aq0[i] = (short)f2bf(x1[i] * cs.x - x2[i] * cs.y);
      Aq1[i] = (short)f2bf(x1[i] * cs.y + x2[i] * cs.x);
    }
  }
  __syncthreads();

  f32x4 O[4];
#pragma unroll
  for (int et = 0; et < 4; ++et) O[et] = (f32x4){0.f, 0.f, 0.f, 0.f};

  // term 1: Qr * Sp
#pragma unroll
  for (int et = 0; et < 4; ++et) {
    bf16x8 B0 = *(const bf16x8*)&SP[16 * et + lr][8 * lg];
    bf16x8 B1 = *(const bf16x8*)&SP[16 * et + lr][8 * lg + 32];
    O[et] = MFMA(Aq0, B0, O[et]);
    O[et] = MFMA(Aq1, B1, O[et]);
  }

  // term 2: diagonal block, strict lower mask; k-tiles kt<=wv only
  for (int kt = 0; kt <= wv; ++kt) {
    const U16* krow = Kr + ((size_t)g * T + k0 + 16 * kt + lr) * DD;
    bf16x8 Bk0 = *(const bf16x8*)(krow + 8 * lg);
    bf16x8 Bk1 = *(const bf16x8*)(krow + 8 * lg + 32);
    f32x4 s = {0.f, 0.f, 0.f, 0.f};
    s = MFMA(Aq0, Bk0, s);
    s = MFMA(Aq1, Bk1, s);
#pragma unroll
    for (int rr = 0; rr < 4; ++rr) {
      int qi = 16 * wv + 4 * lg + rr, ki = 16 * kt + lr;
      float val = (qi > ki) ? s[rr] : 0.f;
      SW[wv][4 * lg + rr][16 * kt + lr] = f2bf(val);
    }
  }
  for (int kt = wv + 1; kt < 4; ++kt) {
#pragma unroll
    for (int rr = 0; rr < 4; ++rr)
      SW[wv][4 * lg + rr][16 * kt + lr] = 0;
  }

  // A-fragments of masked S (same-wave LDS round trip; DS ops are in-order per wave)
  bf16x8 As0 = *(const bf16x8*)&SW[wv][lr][8 * lg];
  bf16x8 As1 = *(const bf16x8*)&SW[wv][lr][8 * lg + 32];

  // PV
#pragma unroll
  for (int et = 0; et < 4; ++et) {
    bf16x8 Bv0 = *(const bf16x8*)&VT[16 * et + lr][8 * lg];
    bf16x8 Bv1 = *(const bf16x8*)&VT[16 * et + lr][8 * lg + 32];
    O[et] = MFMA(As0, Bv0, O[et]);
    O[et] = MFMA(As1, Bv1, O[et]);
  }

  // store f32 output
#pragma unroll
  for (int et = 0; et < 4; ++et)
#pragma unroll
    for (int rr = 0; rr < 4; ++rr)
      Out[((size_t)g * T + q0 + 4 * lg + rr) * DD + 16 * et + lr] = O[et][rr];
}

extern "C" void kernel_launch(void* const* d_in, const int* in_sizes, int n_in,
                              void* d_out, int out_size, void* d_ws, size_t ws_size,
                              hipStream_t stream) {
  const float* Q = (const float*)d_in[0];
  const float* K = (const float*)d_in[1];
  const float* V = (const float*)d_in[2];
  float* Out = (float*)d_out;
  U16* W  = (U16*)d_ws;
  U16* Kr = W;                            // G*T*DD bf16 = 8.39 MB
  U16* Xu = W + 4194304;                  // 8.39 MB
  float2* tab = (float2*)(W + 8388608);   // 4096*32 float2 = 1.05 MB
  k_tab<<<512, 256, 0, stream>>>(tab);
  k_phase1<<<G * NB, 256, 0, stream>>>(K, V, tab, Kr, Xu);
  k_phase2<<<256, 256, 0, stream>>>(Xu);
  k_phase3<<<G * NB, 256, 0, stream>>>(Q, Kr, V, Xu, tab, Out);
}